// Round 7
// baseline (8546.953 us; speedup 1.0000x reference)
//
#include <hip/hip_runtime.h>

// GRU: T=2048, B=64, IN=H=256, L=3, 3H=768.
// v8: v7 (layer-pipelined, fences-every-4) + three latency fixes, no new
// coherence semantics:
//  1. A-stage MFMA split into two passes (c0 tiles, then c1): accA completes
//     at ~half the matrix-pipe time, so gates-c0 VALU overlaps pass-2 MFMA.
//     (bf16 pair packing spans c0/c1 -> gates-c0 stashes hv0, c1 packs+stores.)
//  2. wave0-only flag polling with +1-step lookahead; the end-of-step barrier
//     propagates the guarantee. Removes 8 per-wave ~700cyc MALL reads/step.
//  3. B-stage: h prefetched 1 step ahead into double-buffered LDS via proven
//     global_load_lds (counted vmcnt(4), per-step barrier). Global SOURCE is
//     XOR-swizzled per lane (DMA dest stays linear, m104) so the MFMA-operand
//     ds_read_b128s are 2-way (free) instead of 16-way conflicted.

typedef float  float4_  __attribute__((ext_vector_type(4)));
typedef short  short8_  __attribute__((ext_vector_type(8)));
typedef unsigned short ushort4_ __attribute__((ext_vector_type(4)));
typedef unsigned int   uint4_   __attribute__((ext_vector_type(4)));

#define DEVFN static __device__ __forceinline__

constexpr int T_ = 2048;
constexpr int B_ = 64;
constexpr int H_ = 256;
constexpr int G_ = 768;

// ring geometry (16 slots each)
constexpr int HRING_L  = 16 * 4 * 2048;      // u32 per layer-ring (h pairs)
constexpr int RZRING_L = 16 * 4 * 1024 * 8;  // ushort per layer-ring
constexpr int NRING_L  = 16 * 4 * 1024 * 4;  // float per layer-ring

DEVFN unsigned short f2bf(float f) {
  unsigned u = __float_as_uint(f);
  u += 0x7fffu + ((u >> 16) & 1u);   // round-to-nearest-even
  return (unsigned short)(u >> 16);
}
DEVFN float bf2f(unsigned short s) { return __uint_as_float(((unsigned)s) << 16); }
DEVFN unsigned cvt_pk_bf16(float lo, float hi) {
  unsigned r;
  asm("v_cvt_pk_bf16_f32 %0, %1, %2" : "=v"(r) : "v"(lo), "v"(hi));
  return r;
}
DEVFN float rcp_(float x)  { return __builtin_amdgcn_rcpf(x); }
DEVFN float exp2_(float x) { return __builtin_amdgcn_exp2f(x); }
DEVFN float sigmoid_(float x) { return rcp_(1.f + exp2_(-1.4426950408889634f * x)); }
DEVFN float tanh_(float x)    { return 1.f - 2.f * rcp_(1.f + exp2_(2.8853900817779268f * x)); }

DEVFN void load_lds16(const void* g, void* l) {
  __builtin_amdgcn_global_load_lds(
      (__attribute__((address_space(1))) void*)g,
      (__attribute__((address_space(3))) void*)l, 16, 0, 0);
}

DEVFN void acq_fence() { __builtin_amdgcn_fence(__ATOMIC_ACQUIRE, "agent"); }
DEVFN void rel_fence() { __builtin_amdgcn_fence(__ATOMIC_RELEASE, "agent"); }

DEVFN int pollGE(const int* f, int target) {
  int v = __hip_atomic_load(f, __ATOMIC_RELAXED, __HIP_MEMORY_SCOPE_AGENT);
  while (v < target) {
    __builtin_amdgcn_s_sleep(2);
    v = __hip_atomic_load(f, __ATOMIC_RELAXED, __HIP_MEMORY_SCOPE_AGENT);
  }
  return v;
}
DEVFN void flag_pub(int* f, int v) {
  __hip_atomic_store(f, v, __ATOMIC_RELAXED, __HIP_MEMORY_SCOPE_AGENT);
}

// K-permutation: storage col sc -> original h col (pairs adjacent for cvt_pk).
DEVFN int korig(int sc) { return (sc & ~31) | ((sc & 1) << 4) | ((sc >> 1) & 15); }

// ---------------------------------------------------------------- convert ----
__global__ void convert_kernel(const float* __restrict__ x,
                               const float* __restrict__ wih,
                               const float* __restrict__ whh,
                               const float* __restrict__ bih,
                               const float* __restrict__ bhh,
                               unsigned short* __restrict__ xb,
                               unsigned short* __restrict__ wihb,
                               unsigned short* __restrict__ whhb,
                               float* __restrict__ biasf,
                               float* __restrict__ bhhn,
                               int* __restrict__ flags) {
  const long i0 = (long)blockIdx.x * blockDim.x + threadIdx.x;
  const long stride = (long)gridDim.x * blockDim.x;
  for (long i = i0; i < 32; i += stride) flags[i] = 0;
  for (long i = i0; i < (long)T_ * B_ * H_; i += stride) xb[i] = f2bf(x[i]);
  for (long i = i0; i < 3L * G_ * H_; i += stride) {
    int row = (int)(i >> 8);
    int sc = (int)(i & 255);
    int ko = korig(sc);
    whhb[i] = f2bf(whh[(size_t)row * 256 + ko]);
    wihb[i] = f2bf(wih[(size_t)row * 256 + (row >= G_ ? ko : sc)]);
  }
  for (long i = i0; i < 3L * G_; i += stride) {
    int g = (int)(i % G_);
    biasf[i] = bih[i] + (g < 512 ? bhh[i] : 0.f);
  }
  for (long i = i0; i < 3L * H_; i += stride) {
    int l = (int)(i >> 8), j = (int)(i & 255);
    bhhn[i] = bhh[l * G_ + 512 + j];
  }
}

// ---------------------------------------------------------------- gemm_gx ----
// Layer-0 only: gx = x_bf16 @ Wih^T + bias, stored in gru fragment layout.
__global__ __launch_bounds__(256) void gemm_gx(const unsigned short* __restrict__ A,
                                               const unsigned short* __restrict__ W,
                                               const float* __restrict__ bias,
                                               unsigned short* __restrict__ rzbuf,
                                               float* __restrict__ nbuf) {
  __shared__ alignas(16) unsigned short As[128 * 32];
  __shared__ alignas(16) unsigned short Bs[128 * 32];
  const int tid = threadIdx.x;
  const int bn = blockIdx.x;
  const size_t bm = blockIdx.y;
  const int wave = tid >> 6, lane = tid & 63;
  const int q = lane >> 4, nl = lane & 15;
  const int wr = (wave >> 1) * 64, wc = (wave & 1) * 64;
  const unsigned short* Ab = A + bm * 128 * 256;
  const unsigned short* Wb = W + (size_t)bn * 128 * 256;

  float4_ acc[4][4];
  float4_ z4 = {0.f, 0.f, 0.f, 0.f};
#pragma unroll
  for (int i = 0; i < 4; ++i)
#pragma unroll
    for (int j = 0; j < 4; ++j) acc[i][j] = z4;

  for (int kt = 0; kt < 8; ++kt) {
    const int k0 = kt * 32;
#pragma unroll
    for (int cc = 0; cc < 2; ++cc) {
      int ch = tid + 256 * cc;
      load_lds16(Ab + (size_t)(ch >> 2) * 256 + k0 + (ch & 3) * 8, &As[ch * 8]);
      load_lds16(Wb + (size_t)(ch >> 2) * 256 + k0 + (ch & 3) * 8, &Bs[ch * 8]);
    }
    __syncthreads();
    short8_ af[4], bf[4];
#pragma unroll
    for (int i = 0; i < 4; ++i) {
      af[i] = *(const short8_*)&As[(wr + i * 16 + nl) * 32 + q * 8];
      bf[i] = *(const short8_*)&Bs[(wc + i * 16 + nl) * 32 + q * 8];
    }
#pragma unroll
    for (int i = 0; i < 4; ++i)
#pragma unroll
      for (int j = 0; j < 4; ++j)
        acc[i][j] = __builtin_amdgcn_mfma_f32_16x16x32_bf16(af[i], bf[j], acc[i][j], 0, 0, 0);
    __syncthreads();
  }

  float bv[4];
#pragma unroll
  for (int j = 0; j < 4; ++j) bv[j] = bias[bn * 128 + wc + j * 16 + nl];

  if (bn < 4) {  // r,z -> bf16 fragments
#pragma unroll
    for (int i = 0; i < 4; ++i) {
      const int grow0 = (int)(bm * 128) + wr + i * 16 + q * 4;
      const int t = grow0 >> 6, b = grow0 & 63;
      const size_t tb = ((size_t)(t * 4 + (b >> 4))) * 1024;
      const int qr = (b >> 2) & 3;
      const int g2 = bn >> 1;
#pragma unroll
      for (int j = 0; j < 4; ++j) {
        const int hc = (bn * 128 + wc + j * 16 + nl) & 255;
        const int ch = ((hc >> 4) & 1) * 512 + (hc >> 5) * 64 + qr * 16 + (hc & 15);
        ushort4_ v;
#pragma unroll
        for (int r = 0; r < 4; ++r) v[r] = f2bf(acc[i][j][r] + bv[j]);
        *(ushort4_*)&rzbuf[(tb + ch) * 8 + g2 * 4] = v;
      }
    }
  } else {  // n -> f32 fragments
#pragma unroll
    for (int i = 0; i < 4; ++i) {
      const int grow0 = (int)(bm * 128) + wr + i * 16 + q * 4;
      const int t = grow0 >> 6, b = grow0 & 63;
      const size_t tb = ((size_t)(t * 4 + (b >> 4))) * 1024;
      const int qr = (b >> 2) & 3;
#pragma unroll
      for (int j = 0; j < 4; ++j) {
        const int hc = (bn * 128 + wc + j * 16 + nl) & 255;
        const int ch = ((hc >> 4) & 1) * 512 + (hc >> 5) * 64 + qr * 16 + (hc & 15);
        float4_ v;
#pragma unroll
        for (int r = 0; r < 4; ++r) v[r] = acc[i][j][r] + bv[j];
        *(float4_*)&nbuf[(tb + ch) * 4] = v;
      }
    }
  }
}

// ------------------------------------------------------------------- roles ---
DEVFN void pfA(const unsigned short* rz_src, const float* n_src,
               unsigned short* srz_dst, float* sn_dst, int tid) {
  load_lds16(rz_src + (size_t)tid * 8,         srz_dst + (size_t)tid * 8);
  load_lds16(rz_src + (size_t)(512 + tid) * 8, srz_dst + (size_t)(512 + tid) * 8);
  load_lds16(n_src + (size_t)tid * 4,          sn_dst + (size_t)tid * 4);
  load_lds16(n_src + (size_t)(512 + tid) * 4,  sn_dst + (size_t)(512 + tid) * 4);
}

// A-stage. Per-step vm ops: pf(4) + st(4 for L<=1 / 8 for L==2); end-of-step
// vmcnt(8)/(12) drains pf(t+1)+st(t-1). Publish mini-phase every 4 steps
// (unchanged v7 semantics). wave0 polls with +1-step lookahead; end-of-step
// barrier propagates the guarantee to all waves.
template <int L>
DEVFN void gruA(char* smem,
                const unsigned short* rzsrc, const float* nsrc,
                const unsigned short* whh, const float* bhhn_l,
                const float* h0_l, float* outf, float* hTl,
                unsigned* hring_l, int* fBprod, int* fBself, int* fAself, int b) {
  auto h_bf = (unsigned short(*)[16][272])(smem);              // [2][16][272]
  auto srz  = (unsigned short(*)[8192])(smem + 17408);         // [3][8192]
  auto sn   = (float(*)[4096])(smem + 17408 + 49152);          // [3][4096]

  const int tid = threadIdx.x;
  const int w = tid >> 6, lane = tid & 63;
  const int q = lane >> 4, nl = lane & 15;
  const int cb = w * 32;

  // Whh fragments -> registers (launch_bounds(512,1) => 256-reg budget).
  short8_ wf[6][8];
#pragma unroll
  for (int c = 0; c < 2; ++c)
#pragma unroll
    for (int g = 0; g < 3; ++g) {
      const unsigned short* wrow = whh + (size_t)(g * 256 + cb + c * 16 + nl) * 256;
#pragma unroll
      for (int kt = 0; kt < 8; ++kt)
        wf[c * 3 + g][kt] = *(const short8_*)(wrow + kt * 32 + q * 8);
    }
  const float bn_[2] = { bhhn_l[cb + nl], bhhn_l[cb + 16 + nl] };

  float hold[2][4];
#pragma unroll
  for (int r = 0; r < 4; ++r) {
    hold[0][r] = h0_l[(b * 16 + q * 4 + r) * 256 + cb + nl];
    hold[1][r] = h0_l[(b * 16 + q * 4 + r) * 256 + cb + 16 + nl];
  }
#pragma unroll
  for (int r = 0; r < 4; ++r)
    *(unsigned*)&h_bf[0][q * 4 + r][cb + nl * 2] = cvt_pk_bf16(hold[0][r], hold[1][r]);

  int seenB = 0, seenBs = 0;
  if (L > 0 && w == 0) { seenB = pollGE(fBprod, 4); acq_fence(); }  // gx(0..2) ok
  __builtin_amdgcn_s_barrier();   // propagate wave0's poll before DMA issue
  {
    const size_t b0 = (size_t)b * 1024;
    const size_t b1 = ((size_t)4 + b) * 1024;
    pfA(rzsrc + b0 * 8, nsrc + b0 * 4, &srz[0][0], &sn[0][0], tid);
    pfA(rzsrc + b1 * 8, nsrc + b1 * 4, &srz[1][0], &sn[1][0], tid);
  }
  asm volatile("s_waitcnt vmcnt(4) lgkmcnt(0)" ::: "memory");  // pf(0) done
  __builtin_amdgcn_s_barrier();
  asm volatile("" ::: "memory");

  int b3r = 0;  // LDS buffer holding gx(t)
  for (int t = 0; t < T_; ++t) {
    // ---- publish mini-phase (every 4 steps) — unchanged v7 semantics
    if (((t & 3) == 0) && t >= 4) {
      asm volatile("s_waitcnt vmcnt(0) lgkmcnt(0)" ::: "memory");
      __builtin_amdgcn_s_barrier();
      if (tid == 0) {
        if (L <= 1) rel_fence();     // h-ring data release (wbl2)
        flag_pub(fAself, t);         // L==2: reuse-only flag, no fence
      }
    }
    // ---- wave0-only polls serving step t+1 (barrier at end propagates)
    if (w == 0) {
      if (L > 0 && t + 1 < T_) {
        int tgt = t + 4; if (tgt > T_) tgt = T_;   // covers pf@t+1 (needs t+4)
        if (seenB < tgt) { seenB = pollGE(fBprod, tgt); acq_fence(); }
      }
      if (L <= 1 && t >= 15) {
        int tgt = t - 14;                          // covers overwrite@t+1
        if (seenBs < tgt) seenBs = pollGE(fBself, tgt);
      }
    }
    {  // prefetch gx(t+2) -> LDS buffer (t+2)%3  (covered by poll at t-1)
      const int tt = (t + 2 <= T_ - 1) ? t + 2 : T_ - 1;
      int b3w = b3r + 2; if (b3w >= 3) b3w -= 3;
      const size_t base = (L == 0 ? ((size_t)tt * 4 + b) : ((size_t)(tt & 15) * 4 + b)) * 1024;
      pfA(rzsrc + base * 8, nsrc + base * 4, &srz[b3w][0], &sn[b3w][0], tid);
    }
    asm volatile("" ::: "memory");   // pin pf-before-stores (vmcnt accounting)

    // ---- early gate-operand LDS reads (independent of MFMA)
    const short8_ rzA = *(const short8_*)&srz[b3r][(size_t)tid * 8];
    const short8_ rzB = *(const short8_*)&srz[b3r][(size_t)(512 + tid) * 8];
    const float4_ xnA = *(const float4_*)&sn[b3r][(size_t)tid * 4];
    const float4_ xnB = *(const float4_*)&sn[b3r][(size_t)(512 + tid) * 4];

    // ---- MFMA in two passes: accA (c=0) completes ~half-way -> gates-c0
    // overlaps pass 2's matrix-pipe time.
    float4_ accA[3], accB[3];
    float4_ z4 = {0.f, 0.f, 0.f, 0.f};
#pragma unroll
    for (int u = 0; u < 3; ++u) { accA[u] = z4; accB[u] = z4; }
    __builtin_amdgcn_s_setprio(1);
#pragma unroll
    for (int kt = 0; kt < 8; ++kt) {
      const short8_ af = *(const short8_*)&h_bf[t & 1][nl][kt * 32 + q * 8];
#pragma unroll
      for (int u = 0; u < 3; ++u)
        accA[u] = __builtin_amdgcn_mfma_f32_16x16x32_bf16(af, wf[u][kt], accA[u], 0, 0, 0);
    }
#pragma unroll
    for (int kt = 0; kt < 8; ++kt) {
      const short8_ af = *(const short8_*)&h_bf[t & 1][nl][kt * 32 + q * 8];
#pragma unroll
      for (int u = 0; u < 3; ++u)
        accB[u] = __builtin_amdgcn_mfma_f32_16x16x32_bf16(af, wf[3 + u][kt], accB[u], 0, 0, 0);
    }
    __builtin_amdgcn_s_setprio(0);

    // ---- gates c0 (stash hv0; runs in pass-2's MFMA shadow)
    float hv0s[4];
#pragma unroll
    for (int r = 0; r < 4; ++r) {
      float rr0 = sigmoid_(bf2f((unsigned short)rzA[r]) + accA[0][r]);
      float zz0 = sigmoid_(bf2f((unsigned short)rzA[4 + r]) + accA[1][r]);
      float nn0 = tanh_(xnA[r] + rr0 * (accA[2][r] + bn_[0]));
      hv0s[r] = nn0 + zz0 * (hold[0][r] - nn0);
    }
    // ---- gates c1 + pack + stores
#pragma unroll
    for (int r = 0; r < 4; ++r) {
      float rr1 = sigmoid_(bf2f((unsigned short)rzB[r]) + accB[0][r]);
      float zz1 = sigmoid_(bf2f((unsigned short)rzB[4 + r]) + accB[1][r]);
      float nn1 = tanh_(xnB[r] + rr1 * (accB[2][r] + bn_[1]));
      float hv1 = nn1 + zz1 * (hold[1][r] - nn1);
      hold[0][r] = hv0s[r];
      hold[1][r] = hv1;
      const unsigned pk = cvt_pk_bf16(hv0s[r], hv1);
      *(unsigned*)&h_bf[(t + 1) & 1][q * 4 + r][cb + nl * 2] = pk;
      if (L <= 1)
        hring_l[((size_t)(t & 15) * 4 + b) * 2048 + (size_t)(q * 4 + r) * 128 + (cb >> 1) + nl] = pk;
    }
    if (L == 2) {
      const size_t ob = ((size_t)t * 64 + b * 16) * 256;
#pragma unroll
      for (int r = 0; r < 4; ++r) {
        outf[ob + (size_t)(q * 4 + r) * 256 + cb + nl] = hold[0][r];
        outf[ob + (size_t)(q * 4 + r) * 256 + cb + 16 + nl] = hold[1][r];
      }
    }

    // ---- counted barrier: pf(t+1)+st(t-1) drained; pf(t+2)+st(t) in flight.
    asm volatile("" ::: "memory");
    if (L == 2) asm volatile("s_waitcnt vmcnt(12) lgkmcnt(0)" ::: "memory");
    else        asm volatile("s_waitcnt vmcnt(8) lgkmcnt(0)" ::: "memory");
    __builtin_amdgcn_sched_barrier(0);
    __builtin_amdgcn_s_barrier();
    asm volatile("" ::: "memory");
    b3r = (b3r == 2) ? 0 : b3r + 1;
  }

  // epilogue: final hidden state, then terminal flag
#pragma unroll
  for (int r = 0; r < 4; ++r) {
    hTl[(b * 16 + q * 4 + r) * 256 + cb + nl] = hold[0][r];
    hTl[(b * 16 + q * 4 + r) * 256 + cb + 16 + nl] = hold[1][r];
  }
  asm volatile("s_waitcnt vmcnt(0) lgkmcnt(0)" ::: "memory");
  __builtin_amdgcn_s_barrier();
  if (tid == 0 && fAself) {
    if (L <= 1) rel_fence();
    flag_pub(fAself, T_ + 2);
  }
}

// B-stage: gx_{L+1}(t) = h_L(t) @ Wih^T + bias -> fragment ring.
// h prefetched 1 step ahead into double-buffered LDS (DMA w/ XOR-swizzled
// global source -> conflict-free ds_read_b128). Per-step vm ops: DMA(1)+st(4);
// end-of-step vmcnt(4) drains DMA(t+1)+st(t-1). wave0-only polls (+1 lookahead).
DEVFN void gruB(char* smem,
                const unsigned* hring_l, const unsigned short* wih, const float* bias,
                unsigned short* rzdst, float* ndst,
                int* fAh, int* fAnext, int* fBself, int b) {
  auto hs = (unsigned(*)[2048])(smem);   // [2][2048] u32 = 16 KB
  const int tid = threadIdx.x;
  const int w = tid >> 6, lane = tid & 63;
  const int q = lane >> 4, nl = lane & 15;
  const int cb = w * 32;
  // swizzled global source chunk (16B units): dest chunk = tid (linear)
  const int swc = (tid & ~31) | ((tid & 31) ^ ((tid >> 5) & 7));

  short8_ wf[6][8];
#pragma unroll
  for (int c = 0; c < 2; ++c)
#pragma unroll
    for (int g = 0; g < 3; ++g) {
      const unsigned short* wrow = wih + (size_t)(g * 256 + cb + c * 16 + nl) * 256;
#pragma unroll
      for (int kt = 0; kt < 8; ++kt)
        wf[c * 3 + g][kt] = *(const short8_*)(wrow + kt * 32 + q * 8);
    }
  float bv[6];
#pragma unroll
  for (int c = 0; c < 2; ++c)
#pragma unroll
    for (int g = 0; g < 3; ++g) bv[c * 3 + g] = bias[g * 256 + cb + c * 16 + nl];

  int seenA = 0, seenAn = 0;
  if (w == 0) { seenA = pollGE(fAh, 2); acq_fence(); }   // h(0),h(1) visible
  __builtin_amdgcn_s_barrier();
  load_lds16(hring_l + (size_t)b * 2048 + (size_t)swc * 4, &hs[0][tid * 4]);  // h(0)
  asm volatile("s_waitcnt vmcnt(0) lgkmcnt(0)" ::: "memory");
  __builtin_amdgcn_s_barrier();
  asm volatile("" ::: "memory");

  for (int t = 0; t < T_; ++t) {
    // ---- publish mini-phase (every 4 steps)
    if (((t & 3) == 0) && t >= 4) {
      asm volatile("s_waitcnt vmcnt(0) lgkmcnt(0)" ::: "memory");
      __builtin_amdgcn_s_barrier();
      if (tid == 0) { rel_fence(); flag_pub(fBself, t); }
    }
    // ---- wave0-only polls serving step t+1
    if (w == 0) {
      if (t + 1 < T_) {
        int tgt = t + 3; if (tgt > T_) tgt = T_;   // covers DMA@t+1 (needs t+3)
        if (seenA < tgt) { seenA = pollGE(fAh, tgt); acq_fence(); }
      }
      if (t >= 14 && seenAn < t - 14) seenAn = pollGE(fAnext, t - 14);  // gx reuse
    }
    // ---- DMA h(t+1) -> buf (t+1)&1 (covered by poll at t-1)
    {
      const int tp = (t + 1 < T_) ? t + 1 : T_ - 1;
      load_lds16(hring_l + ((size_t)(tp & 15) * 4 + b) * 2048 + (size_t)swc * 4,
                 &hs[(t + 1) & 1][tid * 4]);
    }
    asm volatile("" ::: "memory");

    // ---- MFMA from hs[t&1] (swizzled reads: 2-way bank, free)
    const unsigned* hb = &hs[t & 1][0];
    float4_ acc[6];
    float4_ z4 = {0.f, 0.f, 0.f, 0.f};
#pragma unroll
    for (int u = 0; u < 6; ++u) acc[u] = z4;
    __builtin_amdgcn_s_setprio(1);
#pragma unroll
    for (int h2 = 0; h2 < 2; ++h2) {
      short8_ af4[4];
#pragma unroll
      for (int k = 0; k < 4; ++k) {
        const int j = (h2 * 4 + k) * 4 + q;
        af4[k] = *(const short8_*)&hb[(nl * 32 + (j ^ (nl & 7))) * 4];
      }
#pragma unroll
      for (int k = 0; k < 4; ++k)
#pragma unroll
        for (int u = 0; u < 6; ++u)
          acc[u] = __builtin_amdgcn_mfma_f32_16x16x32_bf16(af4[k], wf[u][h2 * 4 + k], acc[u], 0, 0, 0);
    }
    __builtin_amdgcn_s_setprio(0);

    const size_t base = ((size_t)(t & 15) * 4 + b) * 1024;
#pragma unroll
    for (int c = 0; c < 2; ++c) {
      const int ch = c * 512 + w * 64 + q * 16 + nl;
      uint4_ rv;
      rv[0] = cvt_pk_bf16(acc[c * 3 + 0][0] + bv[c * 3 + 0], acc[c * 3 + 0][1] + bv[c * 3 + 0]);
      rv[1] = cvt_pk_bf16(acc[c * 3 + 0][2] + bv[c * 3 + 0], acc[c * 3 + 0][3] + bv[c * 3 + 0]);
      rv[2] = cvt_pk_bf16(acc[c * 3 + 1][0] + bv[c * 3 + 1], acc[c * 3 + 1][1] + bv[c * 3 + 1]);
      rv[3] = cvt_pk_bf16(acc[c * 3 + 1][2] + bv[c * 3 + 1], acc[c * 3 + 1][3] + bv[c * 3 + 1]);
      *(uint4_*)(rzdst + (base + ch) * 8) = rv;
      float4_ nv;
#pragma unroll
      for (int r = 0; r < 4; ++r) nv[r] = acc[c * 3 + 2][r] + bv[c * 3 + 2];
      *(float4_*)(ndst + (base + ch) * 4) = nv;
    }

    // ---- counted barrier: DMA(t+1)+st(t-1) drained; st(t) in flight.
    asm volatile("" ::: "memory");
    asm volatile("s_waitcnt vmcnt(4) lgkmcnt(0)" ::: "memory");
    __builtin_amdgcn_sched_barrier(0);
    __builtin_amdgcn_s_barrier();
    asm volatile("" ::: "memory");
  }

  asm volatile("s_waitcnt vmcnt(0) lgkmcnt(0)" ::: "memory");
  __builtin_amdgcn_s_barrier();
  if (tid == 0) { rel_fence(); flag_pub(fBself, T_ + 2); }
}

// -------------------------------------------------------------- pipeline -----
__global__ __launch_bounds__(512, 1) void gru_pipeline(
    const unsigned short* __restrict__ gxrz0, const float* __restrict__ gxn0,
    unsigned short* __restrict__ rzring, float* __restrict__ nring,
    unsigned* __restrict__ hring,
    const unsigned short* __restrict__ whhb, const unsigned short* __restrict__ wihb,
    const float* __restrict__ biasf, const float* __restrict__ bhhn,
    const float* __restrict__ h0, float* __restrict__ out, float* __restrict__ hT,
    int* __restrict__ flags) {
  __shared__ alignas(16) char smem[17408 + 49152 + 49152];
  const int bid = (int)blockIdx.x;
  const int role = bid >> 3, b = bid & 7;
  if (b >= 4) return;   // XCD-chain placement heuristic: chain b on XCD b
  int* fA = flags;        // [3][4]: A-stage progress flags
  int* fB = flags + 12;   // [2][4]: B-stage progress flags

  if (role == 0) {
    gruA<0>(smem, gxrz0, gxn0, whhb, bhhn, h0, nullptr, hT,
            hring, nullptr, &fB[b], &fA[b], b);
  } else if (role == 1) {
    gruB(smem, hring, wihb + (size_t)1 * G_ * H_, biasf + G_,
         rzring, nring, &fA[b], &fA[4 + b], &fB[b], b);
  } else if (role == 2) {
    gruA<1>(smem, rzring, nring, whhb + (size_t)1 * G_ * H_, bhhn + H_,
            h0 + B_ * H_, nullptr, hT + B_ * H_,
            hring + HRING_L, &fB[b], &fB[4 + b], &fA[4 + b], b);
  } else if (role == 3) {
    gruB(smem, hring + HRING_L, wihb + (size_t)2 * G_ * H_, biasf + 2 * G_,
         rzring + RZRING_L, nring + NRING_L, &fA[4 + b], &fA[8 + b], &fB[4 + b], b);
  } else {
    gruA<2>(smem, rzring + RZRING_L, nring + NRING_L, whhb + (size_t)2 * G_ * H_,
            bhhn + 2 * H_, h0 + 2 * B_ * H_, out, hT + 2 * B_ * H_,
            nullptr, &fB[4 + b], nullptr, &fA[8 + b], b);
  }
}

// ------------------------------------------------------------------ launch ---
extern "C" void kernel_launch(void* const* d_in, const int* in_sizes, int n_in,
                              void* d_out, int out_size, void* d_ws, size_t ws_size,
                              hipStream_t stream) {
  (void)in_sizes; (void)n_in; (void)out_size; (void)ws_size;
  const float* x   = (const float*)d_in[0];
  const float* h0  = (const float*)d_in[1];
  const float* wih = (const float*)d_in[2];
  const float* whh = (const float*)d_in[3];
  const float* bih = (const float*)d_in[4];
  const float* bhh = (const float*)d_in[5];
  float* out = (float*)d_out;
  char* ws = (char*)d_ws;

  // workspace layout (within previous 405 MiB footprint)
  unsigned short* gxrz0 = (unsigned short*)(ws + 0);           // 134,217,728
  float*          gxn0  = (float*)(ws + 134217728);            // 134,217,728
  unsigned short* buf0  = (unsigned short*)(ws + 268435456);   //  67,108,864 (x bf16)
  unsigned*       hring = (unsigned*)(ws + 335544320);         //   1,048,576
  unsigned short* rzring= (unsigned short*)(ws + 336592896);   //   2,097,152
  float*          nring = (float*)(ws + 338690048);            //   2,097,152
  int*            flags = (int*)(ws + 340787200);              //         128
  unsigned short* wihb  = (unsigned short*)(ws + 402653184);   //   1,179,648
  unsigned short* whhb  = (unsigned short*)(ws + 403832832);   //   1,179,648
  float*         biasf  = (float*)(ws + 405012480);            //       9,216
  float*          bhhn  = (float*)(ws + 405021696);            //       3,072

  convert_kernel<<<2048, 256, 0, stream>>>(x, wih, whh, bih, bhh,
                                           buf0, wihb, whhb, biasf, bhhn, flags);
  gemm_gx<<<dim3(6, 1024), 256, 0, stream>>>(buf0, wihb, biasf, gxrz0, gxn0);
  gru_pipeline<<<40, 512, 0, stream>>>(gxrz0, gxn0, rzring, nring, hring,
                                       whhb, wihb, biasf, bhhn, h0,
                                       out, out + (size_t)T_ * B_ * H_, flags);
}